// Round 5
// baseline (566.388 us; speedup 1.0000x reference)
//
#include <hip/hip_runtime.h>

#define NN 50000
#define EE 800000
#define FF 128
#define DD 64
#define GG 512

typedef __attribute__((ext_vector_type(8))) short bf8_t;
typedef __attribute__((ext_vector_type(4))) float f4_t;

__device__ __forceinline__ short bf16r(float f) {
    unsigned u = __builtin_bit_cast(unsigned, f);
    u += 0x7fffu + ((u >> 16) & 1u);   // round-to-nearest-even
    return (short)(u >> 16);
}

// ---------------- init: zero cursor + all stats buffers (replay-safe) ----------------

__global__ void zero_all_k(int* __restrict__ cursor, float* __restrict__ stats_all) {
    int i = blockIdx.x * blockDim.x + threadIdx.x;
    if (i < NN) cursor[i] = 0;
    if (i < 7 * 128) stats_all[i] = 0.f;
}

// ---------------- CSR build (counting sort by dst), 4 edges/thread ----------------

__global__ void hist_k(const int* __restrict__ dst, int* __restrict__ deg) {
    int e = (blockIdx.x * 256 + threadIdx.x) * 4;
    if (e + 4 <= EE) {
        int4 d = *(const int4*)&dst[e];
        atomicAdd(&deg[d.x], 1); atomicAdd(&deg[d.y], 1);
        atomicAdd(&deg[d.z], 1); atomicAdd(&deg[d.w], 1);
    } else {
        for (; e < EE; ++e) atomicAdd(&deg[dst[e]], 1);
    }
}

__global__ __launch_bounds__(1024) void scanA_k(const int* __restrict__ deg,
                                                int* __restrict__ rowstart,
                                                int* __restrict__ blocksum) {
    __shared__ int buf[1024];
    int tid = threadIdx.x;
    int base = blockIdx.x * 1024;
    int v = (base + tid < NN) ? deg[base + tid] : 0;
    buf[tid] = v;
    __syncthreads();
    for (int o = 1; o < 1024; o <<= 1) {
        int t = (tid >= o) ? buf[tid - o] : 0;
        __syncthreads();
        buf[tid] += t;
        __syncthreads();
    }
    if (base + tid < NN) rowstart[base + tid + 1] = buf[tid];
    if (tid == 1023) blocksum[blockIdx.x] = buf[1023];
}

__global__ void scanB_k(const int* __restrict__ blocksum, int* __restrict__ bofs, int nb) {
    int lane = threadIdx.x;  // 64 threads
    int v = (lane < nb) ? blocksum[lane] : 0;
    int orig = v;
    for (int o = 1; o < 64; o <<= 1) {
        int t = __shfl_up(v, o);
        if (lane >= o) v += t;
    }
    if (lane < nb) bofs[lane] = v - orig;
}

__global__ void scanC_k(int* __restrict__ rowstart, const int* __restrict__ bofs,
                        int* __restrict__ cursor) {
    int i = blockIdx.x * blockDim.x + threadIdx.x;
    if (i >= NN) return;
    int val = rowstart[i + 1] + bofs[i >> 10];
    rowstart[i + 1] = val;
    if (i + 1 < NN) cursor[i + 1] = val;
    if (i == 0) { rowstart[0] = 0; cursor[0] = 0; }
}

__global__ void fill_k(const int* __restrict__ src, const int* __restrict__ dst,
                       int* __restrict__ cursor, int* __restrict__ csr_src) {
    int e = (blockIdx.x * 256 + threadIdx.x) * 4;
    if (e + 4 <= EE) {
        int4 d = *(const int4*)&dst[e];
        int4 s = *(const int4*)&src[e];
        int p0 = atomicAdd(&cursor[d.x], 1);
        int p1 = atomicAdd(&cursor[d.y], 1);
        int p2 = atomicAdd(&cursor[d.z], 1);
        int p3 = atomicAdd(&cursor[d.w], 1);
        csr_src[p0] = s.x; csr_src[p1] = s.y; csr_src[p2] = s.z; csr_src[p3] = s.w;
    } else {
        for (; e < EE; ++e) { int p = atomicAdd(&cursor[dst[e]], 1); csr_src[p] = src[e]; }
    }
}

// ---------------- GIN aggregation, 16 lanes/node, float4: out = relu(in[i]+sum in[src]+bias) ----------------

__global__ __launch_bounds__(256) void gin_agg_br_k(const float* __restrict__ in,
                                                    const int* __restrict__ rowstart,
                                                    const int* __restrict__ csr_src,
                                                    const float* __restrict__ bias,
                                                    float* __restrict__ out) {
    int gt    = blockIdx.x * 256 + threadIdx.x;
    int node  = gt >> 4;          // 4 nodes per wave, 16 lanes each
    int l16   = threadIdx.x & 15;
    int gbase = threadIdx.x & 48; // group base lane within wave
    int s0 = rowstart[node], s1 = rowstart[node + 1];
    float4 acc = ((const float4*)in)[node * 16 + l16];
    for (int e0 = s0; e0 < s1; e0 += 16) {
        int cnt  = min(16, s1 - e0);
        int srcv = (l16 < cnt) ? csr_src[e0 + l16] : 0;
        for (int j = 0; j < cnt; ++j) {
            int s = __shfl(srcv, gbase + j);
            float4 hv = ((const float4*)in)[s * 16 + l16];
            acc.x += hv.x; acc.y += hv.y; acc.z += hv.z; acc.w += hv.w;
        }
    }
    float4 b = ((const float4*)bias)[l16];
    acc.x = fmaxf(acc.x + b.x, 0.f); acc.y = fmaxf(acc.y + b.y, 0.f);
    acc.z = fmaxf(acc.z + b.z, 0.f); acc.w = fmaxf(acc.w + b.w, 0.f);
    ((float4*)out)[node * 16 + l16] = acc;
}

// ---------------- MFMA GEMM: out[rows x 64] = act(T(in)[rows x K] @ W + b) ----------------
// A fp32 in global, converted to bf16 in-register. W held in VGPR fragments (bf16).
// BNIN: per-column affine a*x+d applied to A before conversion (from bnstats/gamma/beta).
// STATS: per-column sum/sumsq of stored outputs atomically added to gstats (pre-zeroed).
// DUAL: second W/bias/out/stats sharing the same A pass.
// rows must be a multiple of 16. One wave computes 16 rows x 64 cols per step.

template<int K, bool BIAS, bool RELU, bool STATS, bool BNIN, bool DUAL>
__global__ __launch_bounds__(256) void mgemm_k(
    const float* __restrict__ in, const float* __restrict__ W, const float* __restrict__ Wb,
    const float* __restrict__ bias, const float* __restrict__ bias2,
    float* __restrict__ out, float* __restrict__ out2, int rows,
    float* __restrict__ gstats, float* __restrict__ gstats2,
    const float* __restrict__ bnstats, const float* __restrict__ gamma,
    const float* __restrict__ beta)
{
    constexpr int KC = K / 32;
    __shared__ float sA[BNIN ? 64 : 1];
    __shared__ float sD[BNIN ? 64 : 1];
    if (BNIN) {
        if (threadIdx.x < 64) {
            float m = bnstats[threadIdx.x] * (1.f / NN);
            float v = bnstats[64 + threadIdx.x] * (1.f / NN) - m * m;
            float a = rsqrtf(v + 1e-5f) * gamma[threadIdx.x];
            sA[threadIdx.x] = a;
            sD[threadIdx.x] = beta[threadIdx.x] - m * a;
        }
        __syncthreads();
    }
    int lane = threadIdx.x & 63;
    int l15 = lane & 15, lhi = lane >> 4;

    // W fragments: B-operand, lane holds W[kc*32+lhi*8+j][nt*16+l15]
    bf8_t wf[KC][4];
    bf8_t wf2[KC][4];
#pragma unroll
    for (int kc = 0; kc < KC; ++kc)
#pragma unroll
        for (int nt = 0; nt < 4; ++nt) {
            int k0 = kc * 32 + lhi * 8, col = nt * 16 + l15;
            bf8_t v;
#pragma unroll
            for (int j = 0; j < 8; ++j) v[j] = bf16r(W[(k0 + j) * 64 + col]);
            wf[kc][nt] = v;
            if constexpr (DUAL) {
                bf8_t v2;
#pragma unroll
                for (int j = 0; j < 8; ++j) v2[j] = bf16r(Wb[(k0 + j) * 64 + col]);
                wf2[kc][nt] = v2;
            }
        }
    float bi[4], bi2[4];
    if (BIAS) {
#pragma unroll
        for (int nt = 0; nt < 4; ++nt) {
            bi[nt] = bias[nt * 16 + l15];
            if constexpr (DUAL) bi2[nt] = bias2[nt * 16 + l15];
        }
    }

    float ss[4] = {0, 0, 0, 0}, sq[4] = {0, 0, 0, 0};
    float ss2[4] = {0, 0, 0, 0}, sq2[4] = {0, 0, 0, 0};

    int nrb = rows >> 4;
    for (int rb = blockIdx.x * 4 + (threadIdx.x >> 6); rb < nrb; rb += gridDim.x * 4) {
        const float* ap = in + (rb * 16 + l15) * K + lhi * 8;
        bf8_t af[KC];
#pragma unroll
        for (int kc = 0; kc < KC; ++kc) {
            float4 t0 = *(const float4*)(ap + kc * 32);
            float4 t1 = *(const float4*)(ap + kc * 32 + 4);
            if (BNIN) {
                int k0 = kc * 32 + lhi * 8;
                t0.x = sA[k0 + 0] * t0.x + sD[k0 + 0];
                t0.y = sA[k0 + 1] * t0.y + sD[k0 + 1];
                t0.z = sA[k0 + 2] * t0.z + sD[k0 + 2];
                t0.w = sA[k0 + 3] * t0.w + sD[k0 + 3];
                t1.x = sA[k0 + 4] * t1.x + sD[k0 + 4];
                t1.y = sA[k0 + 5] * t1.y + sD[k0 + 5];
                t1.z = sA[k0 + 6] * t1.z + sD[k0 + 6];
                t1.w = sA[k0 + 7] * t1.w + sD[k0 + 7];
            }
            bf8_t v;
            v[0] = bf16r(t0.x); v[1] = bf16r(t0.y); v[2] = bf16r(t0.z); v[3] = bf16r(t0.w);
            v[4] = bf16r(t1.x); v[5] = bf16r(t1.y); v[6] = bf16r(t1.z); v[7] = bf16r(t1.w);
            af[kc] = v;
        }
        f4_t acc[4], acc2[4];
#pragma unroll
        for (int nt = 0; nt < 4; ++nt) {
            acc[nt] = (f4_t){0.f, 0.f, 0.f, 0.f};
            if constexpr (DUAL) acc2[nt] = (f4_t){0.f, 0.f, 0.f, 0.f};
        }
#pragma unroll
        for (int nt = 0; nt < 4; ++nt)
#pragma unroll
            for (int kc = 0; kc < KC; ++kc) {
                acc[nt] = __builtin_amdgcn_mfma_f32_16x16x32_bf16(af[kc], wf[kc][nt], acc[nt], 0, 0, 0);
                if constexpr (DUAL)
                    acc2[nt] = __builtin_amdgcn_mfma_f32_16x16x32_bf16(af[kc], wf2[kc][nt], acc2[nt], 0, 0, 0);
            }
        int orow = rb * 16 + lhi * 4;
#pragma unroll
        for (int nt = 0; nt < 4; ++nt) {
            int col = nt * 16 + l15;
            f4_t a = acc[nt];
            if (BIAS) { a[0] += bi[nt]; a[1] += bi[nt]; a[2] += bi[nt]; a[3] += bi[nt]; }
            if (RELU) {
                a[0] = fmaxf(a[0], 0.f); a[1] = fmaxf(a[1], 0.f);
                a[2] = fmaxf(a[2], 0.f); a[3] = fmaxf(a[3], 0.f);
            }
            out[(orow + 0) * 64 + col] = a[0];
            out[(orow + 1) * 64 + col] = a[1];
            out[(orow + 2) * 64 + col] = a[2];
            out[(orow + 3) * 64 + col] = a[3];
            if (STATS) {
                ss[nt] += a[0] + a[1] + a[2] + a[3];
                sq[nt] += a[0] * a[0] + a[1] * a[1] + a[2] * a[2] + a[3] * a[3];
            }
            if constexpr (DUAL) {
                f4_t b = acc2[nt];
                if (BIAS) { b[0] += bi2[nt]; b[1] += bi2[nt]; b[2] += bi2[nt]; b[3] += bi2[nt]; }
                if (RELU) {
                    b[0] = fmaxf(b[0], 0.f); b[1] = fmaxf(b[1], 0.f);
                    b[2] = fmaxf(b[2], 0.f); b[3] = fmaxf(b[3], 0.f);
                }
                out2[(orow + 0) * 64 + col] = b[0];
                out2[(orow + 1) * 64 + col] = b[1];
                out2[(orow + 2) * 64 + col] = b[2];
                out2[(orow + 3) * 64 + col] = b[3];
                if (STATS) {
                    ss2[nt] += b[0] + b[1] + b[2] + b[3];
                    sq2[nt] += b[0] * b[0] + b[1] * b[1] + b[2] * b[2] + b[3] * b[3];
                }
            }
        }
    }
    if (STATS) {
#pragma unroll
        for (int nt = 0; nt < 4; ++nt) {
            float s = ss[nt]; s += __shfl_xor(s, 16); s += __shfl_xor(s, 32);
            float q = sq[nt]; q += __shfl_xor(q, 16); q += __shfl_xor(q, 32);
            if (lhi == 0) {
                atomicAdd(&gstats[nt * 16 + l15], s);
                atomicAdd(&gstats[64 + nt * 16 + l15], q);
            }
            if constexpr (DUAL) {
                float s2 = ss2[nt]; s2 += __shfl_xor(s2, 16); s2 += __shfl_xor(s2, 32);
                float q2 = sq2[nt]; q2 += __shfl_xor(q2, 16); q2 += __shfl_xor(q2, 32);
                if (lhi == 0) {
                    atomicAdd(&gstats2[nt * 16 + l15], s2);
                    atomicAdd(&gstats2[64 + nt * 16 + l15], q2);
                }
            }
        }
    }
}

// ---------------- batchnorm apply ----------------

__global__ void bn_apply_k(const float* __restrict__ in, float* __restrict__ out, int rows,
                           const float* __restrict__ stats, const float* __restrict__ gamma,
                           const float* __restrict__ beta) {
    int n = rows * 64;
    float invr = 1.f / (float)rows;
    for (int i = blockIdx.x * blockDim.x + threadIdx.x; i < n; i += gridDim.x * blockDim.x) {
        int c = i & 63;
        float m   = stats[c] * invr;
        float var = stats[64 + c] * invr - m * m;
        out[i] = (in[i] - m) * rsqrtf(var + 1e-5f) * gamma[c] + beta[c];
    }
}

// ---------------- noisy = attn * BN(z) + noise (fp32) ----------------

__global__ void noisy_bn_k(const float* __restrict__ z, const float* __restrict__ stats,
                           const float* __restrict__ gamma, const float* __restrict__ beta,
                           const float* __restrict__ attn, const float* __restrict__ noise,
                           float* __restrict__ out) {
    int total = NN * 64;
    for (int i = blockIdx.x * blockDim.x + threadIdx.x; i < total; i += gridDim.x * blockDim.x) {
        int c = i & 63, n = i >> 6;
        float m   = stats[c] * (1.f / NN);
        float var = stats[64 + c] * (1.f / NN) - m * m;
        float a   = rsqrtf(var + 1e-5f) * gamma[c];
        float d   = beta[c] - m * a;
        out[i] = attn[n] * (a * z[i] + d) + noise[i];
    }
}

// ---------------- segment boundaries (batch is sorted) ----------------

__global__ void seg_bounds_k(const int* __restrict__ batch, int* __restrict__ segstart) {
    int g = blockIdx.x * blockDim.x + threadIdx.x;
    if (g > GG) return;
    int lo = 0, hi = NN;
    while (lo < hi) {
        int mid = (lo + hi) >> 1;
        if (batch[mid] < g) lo = mid + 1; else hi = mid;
    }
    segstart[g] = lo;
}

// ---------------- mean pooling with fused BN affine: slots = a*mean(z)+d ----------------

__global__ __launch_bounds__(256) void graph_mean_bn_k(const float* __restrict__ z,
                                                       const int* __restrict__ segst,
                                                       const float* __restrict__ stats,
                                                       const float* __restrict__ gamma,
                                                       const float* __restrict__ beta,
                                                       float* __restrict__ slots) {
    int g = blockIdx.x, tid = threadIdx.x, w = tid >> 6, lane = tid & 63;
    int s0 = segst[g], s1 = segst[g + 1];
    float acc = 0.f;
    for (int n = s0 + w; n < s1; n += 4) acc += z[n * 64 + lane];
    __shared__ float red[256];
    red[tid] = acc;
    __syncthreads();
    if (tid < 64) {
        float m   = stats[tid] * (1.f / NN);
        float var = stats[64 + tid] * (1.f / NN) - m * m;
        float a   = rsqrtf(var + 1e-5f) * gamma[tid];
        float d   = beta[tid] - m * a;
        float mean = (red[tid] + red[64 + tid] + red[128 + tid] + red[192 + tid])
                   / (float)max(s1 - s0, 1);
        slots[g * 64 + tid] = a * mean + d;
    }
}

// ---------------- fused attention iteration: q -> logits -> softmax -> updates -> GRU ----------------

__global__ __launch_bounds__(256) void attn_iter_k(
    const float* __restrict__ kbuf, const float* __restrict__ vbuf,
    float* __restrict__ slots, const int* __restrict__ segst,
    const float* __restrict__ Wq,
    const float* __restrict__ Wih, const float* __restrict__ Whh,
    const float* __restrict__ bih, const float* __restrict__ bhh,
    float* __restrict__ attn, int final_iter)
{
    int g = blockIdx.x, tid = threadIdx.x, w = tid >> 6, lane = tid & 63;
    __shared__ float ssl[64], sq[64], sred[256], supd[64], ssum[4];
    __shared__ float sgi[192], sgh[192];
    __shared__ float smax, sstot;

    if (tid < 64) ssl[tid] = slots[g * 64 + tid];
    __syncthreads();
    // q = slots[g] @ Wq  (each wave does 16 of the K terms)
    {
        float p = 0.f;
#pragma unroll
        for (int kk = 0; kk < 16; ++kk) p += ssl[w * 16 + kk] * Wq[(w * 16 + kk) * 64 + lane];
        sred[tid] = p;
    }
    __syncthreads();
    if (tid < 64) sq[tid] = sred[tid] + sred[64 + tid] + sred[128 + tid] + sred[192 + tid];
    __syncthreads();

    int s0 = segst[g], s1 = segst[g + 1];
    float qd = sq[lane];

    // pass 1: logits (stored raw in attn[]) + max
    float m = -INFINITY;
    for (int n = s0 + w; n < s1; n += 4) {
        float p = kbuf[n * 64 + lane] * qd;
        p += __shfl_xor(p, 1);  p += __shfl_xor(p, 2);  p += __shfl_xor(p, 4);
        p += __shfl_xor(p, 8);  p += __shfl_xor(p, 16); p += __shfl_xor(p, 32);
        p *= 0.125f;  // 1/sqrt(64)
        if (lane == 0) attn[n] = p;
        m = fmaxf(m, p);
    }
    if (lane == 0) sred[w] = m;
    __syncthreads();
    if (tid == 0) smax = fmaxf(fmaxf(sred[0], sred[1]), fmaxf(sred[2], sred[3]));
    __syncthreads();
    m = smax;

    // pass 2: e = exp(l-m) (stored in attn[]), sum + weighted v accumulation
    float s = 0.f, upd = 0.f;
    for (int n = s0 + w; n < s1; n += 4) {
        float e = expf(attn[n] - m);
        if (lane == 0) attn[n] = e;
        s += e;
        upd += e * vbuf[n * 64 + lane];
    }
    sred[tid] = upd;
    if (lane == 0) ssum[w] = s;
    __syncthreads();
    if (tid < 64) {
        float st = ssum[0] + ssum[1] + ssum[2] + ssum[3] + 1e-9f;
        if (tid == 0) sstot = st;
        supd[tid] = (sred[tid] + sred[64 + tid] + sred[128 + tid] + sred[192 + tid]) / st;
    }
    __syncthreads();

    if (final_iter) {
        float inv = 1.f / sstot;
        for (int n = s0 + tid; n < s1; n += 256) attn[n] *= inv;
    }

    // GRU: slots = (1-z)*n + z*h
    if (tid < 192) {
        float a = bih[tid], b = bhh[tid];
        const float* wi = &Wih[tid * 64];
        const float* wh = &Whh[tid * 64];
#pragma unroll 8
        for (int j = 0; j < 64; ++j) { a += supd[j] * wi[j]; b += ssl[j] * wh[j]; }
        sgi[tid] = a; sgh[tid] = b;
    }
    __syncthreads();
    if (tid < 64) {
        float r  = 1.f / (1.f + expf(-(sgi[tid] + sgh[tid])));
        float z  = 1.f / (1.f + expf(-(sgi[64 + tid] + sgh[64 + tid])));
        float nn = tanhf(sgi[128 + tid] + r * sgh[128 + tid]);
        slots[g * 64 + tid] = (1.f - z) * nn + z * ssl[tid];
    }
}

// ---------------- host side ----------------

extern "C" void kernel_launch(void* const* d_in, const int* in_sizes, int n_in,
                              void* d_out, int out_size, void* d_ws, size_t ws_size,
                              hipStream_t stream) {
    (void)in_sizes; (void)n_in; (void)out_size; (void)ws_size;

    const float* x      = (const float*)d_in[0];
    const int*   ei     = (const int*)d_in[1];
    const int*   srcI   = ei;
    const int*   dstI   = ei + EE;
    const int*   batch  = (const int*)d_in[2];
    const float* noise  = (const float*)d_in[3];
    const float* W1_0   = (const float*)d_in[4];
    const float* b1_0   = (const float*)d_in[5];
    const float* W2_0   = (const float*)d_in[6];
    const float* b2_0   = (const float*)d_in[7];
    const float* W1_r   = (const float*)d_in[8];
    const float* b1_r   = (const float*)d_in[9];
    const float* W2_r   = (const float*)d_in[10];
    const float* b2_r   = (const float*)d_in[11];
    const float* bn_g   = (const float*)d_in[12];
    const float* bn_b   = (const float*)d_in[13];
    const float* Wq     = (const float*)d_in[14];
    const float* Wk     = (const float*)d_in[15];
    const float* Wv     = (const float*)d_in[16];
    const float* Wih    = (const float*)d_in[17];
    const float* Whh    = (const float*)d_in[18];
    const float* bih    = (const float*)d_in[19];
    const float* bhh    = (const float*)d_in[20];
    const float* nmW    = (const float*)d_in[21];
    const float* nmb    = (const float*)d_in[22];
    const float* nlW    = (const float*)d_in[23];
    const float* nlb    = (const float*)d_in[24];
    const float* gmW    = (const float*)d_in[25];
    const float* gmb    = (const float*)d_in[26];
    const float* glW    = (const float*)d_in[27];
    const float* glb    = (const float*)d_in[28];
    const float* pj_g   = (const float*)d_in[29];
    const float* pj_b   = (const float*)d_in[30];

    float* ws      = (float*)d_ws;
    float* B0      = ws;                       // NN*DD
    float* B1      = B0 + NN * DD;             // NN*DD
    float* B2      = B1 + NN * DD;             // NN*DD
    float* B3      = B2 + NN * DD;             // NN*DD
    float* slots   = B3 + NN * DD;             // GG*DD
    float* gpre1   = slots + GG * DD;          // GG*DD
    float* gpre2   = gpre1 + GG * DD;          // GG*DD
    float* attn    = gpre2 + GG * DD;          // NN
    float* stats   = attn + NN;                // 7*128
    int*   segst   = (int*)(stats + 7 * 128);  // GG+1
    int*   rowst   = segst + GG + 1;           // NN+1
    int*   cursor  = rowst + NN + 1;           // NN
    int*   bsum    = cursor + NN;              // 64
    int*   bofs    = bsum + 64;                // 64
    int*   csr_src = bofs + 64;                // EE

    float* s0 = stats, *s1 = stats + 128, *s2 = stats + 256, *s3 = stats + 384,
         * s4 = stats + 512, *s5 = stats + 640, *s6 = stats + 768;

    float* outp = (float*)d_out;
    float* out_nmu = outp;
    float* out_nlv = outp + NN * DD;
    float* out_gmu = outp + 2 * NN * DD;
    float* out_glv = outp + 2 * NN * DD + GG * DD;

    constexpr int NB = (NN + 1023) / 1024;  // 49 scan chunks
    constexpr int GE4 = (EE / 4 + 255) / 256;
    const float* np = nullptr;
    float* zp = nullptr;

#define GK(...) <<<__VA_ARGS__, 0, stream>>>
    // ---------- init + CSR build + segments ----------
    zero_all_k GK((NN + 255) / 256, 256)(cursor, stats);
    hist_k GK(GE4, 256)(dstI, cursor);
    scanA_k GK(NB, 1024)(cursor, rowst, bsum);
    scanB_k GK(1, 64)(bsum, bofs, NB);
    scanC_k GK((NN + 255) / 256, 256)(rowst, bofs, cursor);
    fill_k GK(GE4, 256)(srcI, dstI, cursor, csr_src);
    seg_bounds_k GK(3, 256)(batch, segst);

    // ---------- GIN layer 0 (GEMM-first: gather on 64-wide) ----------
    mgemm_k<128, false, false, false, false, false> GK(512, 256)
        (x, W1_0, np, np, np, B0, zp, NN, zp, zp, np, np, np);
    gin_agg_br_k GK(3125, 256)(B0, rowst, csr_src, b1_0, B1);
    mgemm_k<64, true, true, true, false, false> GK(512, 256)
        (B1, W2_0, np, b2_0, np, B2, zp, NN, s0, zp, np, np, np);

    // ---------- GIN layer 1 (BN0 affine fused into A-load) ----------
    mgemm_k<64, false, false, false, true, false> GK(512, 256)
        (B2, W1_r, np, np, np, B0, zp, NN, zp, zp, s0, bn_g + 0, bn_b + 0);
    gin_agg_br_k GK(3125, 256)(B0, rowst, csr_src, b1_r, B1);
    mgemm_k<64, true, true, true, false, false> GK(512, 256)
        (B1, W2_r, np, b2_r, np, B2, zp, NN, s1, zp, np, np, np);

    // ---------- GIN layer 2 ----------
    mgemm_k<64, false, false, false, true, false> GK(512, 256)
        (B2, W1_r + DD * DD, np, np, np, B0, zp, NN, zp, zp, s1, bn_g + 64, bn_b + 64);
    gin_agg_br_k GK(3125, 256)(B0, rowst, csr_src, b1_r + DD, B1);
    mgemm_k<64, true, true, true, false, false> GK(512, 256)
        (B1, W2_r + DD * DD, np, b2_r + DD, np, B2, zp, NN, s2, zp, np, np, np);
    // B2 = z2 (pre-BN); final BN affine (s2, bn[2]) fused into all consumers.

    // ---------- summary maker ----------
    graph_mean_bn_k GK(GG, 256)(B2, segst, s2, bn_g + 128, bn_b + 128, slots);
    mgemm_k<64, false, false, false, true, true> GK(512, 256)   // k,v in one pass
        (B2, Wk, Wv, np, np, B0, B1, NN, zp, zp, s2, bn_g + 128, bn_b + 128);
    attn_iter_k GK(GG, 256)(B0, B1, slots, segst, Wq, Wih, Whh, bih, bhh, attn, 0);
    attn_iter_k GK(GG, 256)(B0, B1, slots, segst, Wq, Wih, Whh, bih, bhh, attn, 1);

    // ---------- node heads ----------
    noisy_bn_k GK(2048, 256)(B2, s2, bn_g + 128, bn_b + 128, attn, noise, B3);
    mgemm_k<64, true, true, true, false, true> GK(512, 256)
        (B3, nmW, nlW, nmb, nlb, B0, B1, NN, s3, s4, np, np, np);
    bn_apply_k GK(2048, 256)(B0, out_nmu, NN, s3, pj_g + 0, pj_b + 0);
    bn_apply_k GK(2048, 256)(B1, out_nlv, NN, s4, pj_g + 64, pj_b + 64);

    // ---------- graph heads ----------
    mgemm_k<64, true, true, true, false, true> GK(8, 256)
        (slots, gmW, glW, gmb, glb, gpre1, gpre2, GG, s5, s6, np, np, np);
    bn_apply_k GK(128, 256)(gpre1, out_gmu, GG, s5, pj_g + 128, pj_b + 128);
    bn_apply_k GK(128, 256)(gpre2, out_glv, GG, s6, pj_g + 192, pj_b + 192);
#undef GK
}